// Round 1
// baseline (518.683 us; speedup 1.0000x reference)
//
#include <hip/hip_runtime.h>
#include <hip/hip_bf16.h>

typedef __bf16 bf16;
typedef __bf16 bf16x8 __attribute__((ext_vector_type(8)));
typedef __bf16 bf16x4v __attribute__((ext_vector_type(4)));
typedef float f32x4 __attribute__((ext_vector_type(4)));
typedef float float4v __attribute__((ext_vector_type(4)));

#define MFMA16(a, b, c) __builtin_amdgcn_mfma_f32_16x16x32_bf16(a, b, c, 0, 0, 0)

__device__ __forceinline__ void async_load16(const bf16* g, bf16* l) {
    __builtin_amdgcn_global_load_lds(
        (const __attribute__((address_space(1))) void*)g,
        (__attribute__((address_space(3))) void*)l,
        16, 0, 0);
}

// ---------------- cast x (f32 -> bf16), vectorized ----------------
__global__ void k_cast_x(const float* __restrict__ x, bf16* __restrict__ xb, int n4) {
    int i = blockIdx.x * blockDim.x + threadIdx.x;
    if (i < n4) {
        float4v v = ((const float4v*)x)[i];
        bf16x4v o;
        o.x = (bf16)v.x; o.y = (bf16)v.y; o.z = (bf16)v.z; o.w = (bf16)v.w;
        ((bf16x4v*)xb)[i] = o;
    }
}

// ---------------- transpose + cast W (f32 [R][Cc] -> bf16 [Cc][R]) ----------------
__global__ void k_trans_cast(const float* __restrict__ W, bf16* __restrict__ WT, int R, int Cc) {
    __shared__ float tile[32][33];
    int r0 = blockIdx.y * 32, c0 = blockIdx.x * 32;
    int tx = threadIdx.x & 31, ty = threadIdx.x >> 5;  // 256 thr: ty 0..7
#pragma unroll
    for (int i = 0; i < 32; i += 8)
        tile[ty + i][tx] = W[(size_t)(r0 + ty + i) * Cc + c0 + tx];
    __syncthreads();
#pragma unroll
    for (int i = 0; i < 32; i += 8)
        WT[(size_t)(c0 + ty + i) * R + r0 + tx] = (bf16)tile[tx][ty + i];
}

// ---------------- QKV GEMM: [8192x1024] x [1024x3072] with scatter epilogue ----------------
// A row-major bf16, BT = W^T row-major bf16 [3072][1024].
// q,k -> [B][H][T][64], v -> transposed [B][H][64][T]
__global__ __launch_bounds__(256, 2) void k_gemm_qkv(
    const bf16* __restrict__ A, const bf16* __restrict__ BT,
    const float* __restrict__ bias,
    bf16* __restrict__ qo, bf16* __restrict__ ko, bf16* __restrict__ vo) {
    __shared__ bf16 As[128 * 32];
    __shared__ bf16 Bs[128 * 32];
    const int K = 1024;
    int row0 = blockIdx.y * 128;
    int col0 = blockIdx.x * 128;
    int lane = threadIdx.x & 63, w = threadIdx.x >> 6;
    int wr = w >> 1, wc = w & 1;
    f32x4 acc[4][4] = {};
    const bf16* Ag = A + (size_t)(row0 + (lane >> 2)) * K + (lane & 3) * 8;
    const bf16* Bg = BT + (size_t)(col0 + (lane >> 2)) * K + (lane & 3) * 8;

    for (int k0 = 0; k0 < K; k0 += 32) {
#pragma unroll
        for (int i = 0; i < 2; ++i) {
            async_load16(Ag + (size_t)(i * 64 + w * 16) * K + k0, &As[(i * 64 + w * 16) * 32]);
            async_load16(Bg + (size_t)(i * 64 + w * 16) * K + k0, &Bs[(i * 64 + w * 16) * 32]);
        }
        __syncthreads();
        bf16x8 af[4], bfr[4];
#pragma unroll
        for (int m = 0; m < 4; ++m)
            af[m] = *(const bf16x8*)&As[(wr * 64 + m * 16 + (lane & 15)) * 32 + (lane >> 4) * 8];
#pragma unroll
        for (int n = 0; n < 4; ++n)
            bfr[n] = *(const bf16x8*)&Bs[(wc * 64 + n * 16 + (lane & 15)) * 32 + (lane >> 4) * 8];
#pragma unroll
        for (int m = 0; m < 4; ++m)
#pragma unroll
            for (int n = 0; n < 4; ++n)
                acc[m][n] = MFMA16(af[m], bfr[n], acc[m][n]);
        __syncthreads();
    }

    int trow = row0 + wr * 64 + ((lane >> 4) * 4);
    int tcol = col0 + wc * 64 + (lane & 15);
#pragma unroll
    for (int m = 0; m < 4; ++m)
#pragma unroll
        for (int n = 0; n < 4; ++n) {
            int cg = tcol + n * 16;
            float bi = bias[cg];
#pragma unroll
            for (int j = 0; j < 4; ++j) {
                int rg = trow + m * 16 + j;
                float val = acc[m][n][j] + bi;
                bf16 hv = (bf16)val;
                int b = rg >> 11, t = rg & 2047;
                if (cg < 1024) {
                    int h = cg >> 6, d = cg & 63;
                    qo[(size_t)((b * 16 + h) * 2048 + t) * 64 + d] = hv;
                } else if (cg < 2048) {
                    int c2 = cg - 1024;
                    int h = c2 >> 6, d = c2 & 63;
                    ko[(size_t)((b * 16 + h) * 2048 + t) * 64 + d] = hv;
                } else {
                    int c2 = cg - 2048;
                    int h = c2 >> 6, d = c2 & 63;
                    vo[(size_t)((b * 16 + h) * 64 + d) * 2048 + t] = hv;
                }
            }
        }
}

// ---------------- flash attention (causal), 4 independent waves x 32 Q-rows ----------------
__global__ __launch_bounds__(256, 2) void k_attn(
    const bf16* __restrict__ qg, const bf16* __restrict__ kg,
    const bf16* __restrict__ vg, bf16* __restrict__ y) {
    __shared__ __align__(16) unsigned char Ps[4][4096];  // per-wave 32x64 bf16, swizzled
    int bh = blockIdx.y;
    int qt0 = blockIdx.x * 128;
    int lane = threadIdx.x & 63, w = threadIdx.x >> 6;
    int b = bh >> 4;
    const bf16* Qh = qg + (size_t)bh * 2048 * 64;
    const bf16* Kh = kg + (size_t)bh * 2048 * 64;
    const bf16* Vh = vg + (size_t)bh * 64 * 2048;
    int trow0 = qt0 + w * 32;

    bf16x8 qf[2][2];
#pragma unroll
    for (int mi = 0; mi < 2; ++mi)
#pragma unroll
        for (int kc = 0; kc < 2; ++kc)
            qf[mi][kc] = *(const bf16x8*)&Qh[(size_t)(trow0 + mi * 16 + (lane & 15)) * 64 + kc * 32 + (lane >> 4) * 8];

    f32x4 acc_o[2][4] = {};
    float mst[2][4], lst[2][4];
#pragma unroll
    for (int mi = 0; mi < 2; ++mi)
#pragma unroll
        for (int j = 0; j < 4; ++j) { mst[mi][j] = -1e30f; lst[mi][j] = 0.f; }

    unsigned char* myPs = Ps[w];
    int smax = trow0 + 32;
    for (int s0 = 0; s0 < smax; s0 += 64) {
        f32x4 accs[2][4] = {};
#pragma unroll
        for (int nt = 0; nt < 4; ++nt)
#pragma unroll
            for (int kc = 0; kc < 2; ++kc) {
                bf16x8 kf = *(const bf16x8*)&Kh[(size_t)(s0 + nt * 16 + (lane & 15)) * 64 + kc * 32 + (lane >> 4) * 8];
#pragma unroll
                for (int mi = 0; mi < 2; ++mi)
                    accs[mi][nt] = MFMA16(qf[mi][kc], kf, accs[mi][nt]);
            }
        bool diag = (s0 + 63 >= trow0 + 0) && (s0 + 63 > trow0);  // mask needed iff tile crosses diagonal
#pragma unroll
        for (int mi = 0; mi < 2; ++mi) {
            float corr[4];
#pragma unroll
            for (int j = 0; j < 4; ++j) {
                int t = trow0 + mi * 16 + (lane >> 4) * 4 + j;
                float rm = -1e30f;
#pragma unroll
                for (int nt = 0; nt < 4; ++nt) {
                    float vsc = accs[mi][nt][j] * 0.125f;
                    if (diag) {
                        int s = s0 + nt * 16 + (lane & 15);
                        if (s > t) vsc = -1e30f;
                    }
                    accs[mi][nt][j] = vsc;
                    rm = fmaxf(rm, vsc);
                }
#pragma unroll
                for (int off = 1; off < 16; off <<= 1) rm = fmaxf(rm, __shfl_xor(rm, off));
                float mo = mst[mi][j];
                float mn = fmaxf(mo, rm);
                float c = __expf(mo - mn);
                float rs = 0.f;
#pragma unroll
                for (int nt = 0; nt < 4; ++nt) {
                    float p = __expf(accs[mi][nt][j] - mn);
                    accs[mi][nt][j] = p;
                    rs += p;
                }
#pragma unroll
                for (int off = 1; off < 16; off <<= 1) rs += __shfl_xor(rs, off);
                mst[mi][j] = mn;
                lst[mi][j] = lst[mi][j] * c + rs;
                corr[j] = c;
            }
#pragma unroll
            for (int nt = 0; nt < 4; ++nt)
#pragma unroll
                for (int j = 0; j < 4; ++j)
                    acc_o[mi][nt][j] *= corr[j];
            // write P tile to LDS (XOR-swizzled rows: bank-conflict-free b128 reads)
#pragma unroll
            for (int nt = 0; nt < 4; ++nt)
#pragma unroll
                for (int j = 0; j < 4; ++j) {
                    int row = mi * 16 + (lane >> 4) * 4 + j;
                    int byteofs = row * 128 + ((((nt * 16 + (lane & 15)) * 2)) ^ ((row & 7) << 4));
                    *(bf16*)&myPs[byteofs] = (bf16)accs[mi][nt][j];
                }
        }
        asm volatile("s_waitcnt lgkmcnt(0)" ::: "memory");
        // PV: A = P (from LDS), B = V^T rows (contiguous s)
#pragma unroll
        for (int ks = 0; ks < 2; ++ks) {
            bf16x8 pa[2];
#pragma unroll
            for (int mi = 0; mi < 2; ++mi) {
                int row = mi * 16 + (lane & 15);
                int byteofs = row * 128 + ((ks * 64 + (lane >> 4) * 16) ^ ((row & 7) << 4));
                pa[mi] = *(const bf16x8*)&myPs[byteofs];
            }
#pragma unroll
            for (int nt = 0; nt < 4; ++nt) {
                bf16x8 vf = *(const bf16x8*)&Vh[(size_t)(nt * 16 + (lane & 15)) * 2048 + s0 + ks * 32 + (lane >> 4) * 8];
#pragma unroll
                for (int mi = 0; mi < 2; ++mi)
                    acc_o[mi][nt] = MFMA16(pa[mi], vf, acc_o[mi][nt]);
            }
        }
    }
    int hcol = (bh & 15) * 64;
#pragma unroll
    for (int mi = 0; mi < 2; ++mi)
#pragma unroll
        for (int nt = 0; nt < 4; ++nt)
#pragma unroll
            for (int j = 0; j < 4; ++j) {
                int t = trow0 + mi * 16 + (lane >> 4) * 4 + j;
                int d = nt * 16 + (lane & 15);
                float val = acc_o[mi][nt][j] / lst[mi][j];
                y[(size_t)(b * 2048 + t) * 1024 + hcol + d] = (bf16)val;
            }
}

// ---------------- proj GEMM: y[8192x1024] x Wp[1024x1024] + bias -> f32 out ----------------
__global__ __launch_bounds__(256, 2) void k_gemm_proj(
    const bf16* __restrict__ A, const bf16* __restrict__ BT,
    const float* __restrict__ bias, float* __restrict__ out) {
    __shared__ bf16 As[128 * 32];
    __shared__ bf16 Bs[128 * 32];
    const int K = 1024;
    int row0 = blockIdx.y * 128;
    int col0 = blockIdx.x * 128;
    int lane = threadIdx.x & 63, w = threadIdx.x >> 6;
    int wr = w >> 1, wc = w & 1;
    f32x4 acc[4][4] = {};
    const bf16* Ag = A + (size_t)(row0 + (lane >> 2)) * K + (lane & 3) * 8;
    const bf16* Bg = BT + (size_t)(col0 + (lane >> 2)) * K + (lane & 3) * 8;

    for (int k0 = 0; k0 < K; k0 += 32) {
#pragma unroll
        for (int i = 0; i < 2; ++i) {
            async_load16(Ag + (size_t)(i * 64 + w * 16) * K + k0, &As[(i * 64 + w * 16) * 32]);
            async_load16(Bg + (size_t)(i * 64 + w * 16) * K + k0, &Bs[(i * 64 + w * 16) * 32]);
        }
        __syncthreads();
        bf16x8 af[4], bfr[4];
#pragma unroll
        for (int m = 0; m < 4; ++m)
            af[m] = *(const bf16x8*)&As[(wr * 64 + m * 16 + (lane & 15)) * 32 + (lane >> 4) * 8];
#pragma unroll
        for (int n = 0; n < 4; ++n)
            bfr[n] = *(const bf16x8*)&Bs[(wc * 64 + n * 16 + (lane & 15)) * 32 + (lane >> 4) * 8];
#pragma unroll
        for (int m = 0; m < 4; ++m)
#pragma unroll
            for (int n = 0; n < 4; ++n)
                acc[m][n] = MFMA16(af[m], bfr[n], acc[m][n]);
        __syncthreads();
    }

    int trow = row0 + wr * 64 + ((lane >> 4) * 4);
    int tcol = col0 + wc * 64 + (lane & 15);
#pragma unroll
    for (int m = 0; m < 4; ++m)
#pragma unroll
        for (int n = 0; n < 4; ++n) {
            int cg = tcol + n * 16;
            float bi = bias[cg];
#pragma unroll
            for (int j = 0; j < 4; ++j) {
                int rg = trow + m * 16 + j;
                out[(size_t)rg * 1024 + cg] = acc[m][n][j] + bi;
            }
        }
}

// ---------------- new_memory = x[:, 1536:, :] (f32 copy) ----------------
__global__ void k_copy_mem(const float* __restrict__ x, float* __restrict__ out2) {
    int o4 = blockIdx.x * blockDim.x + threadIdx.x;  // float4 index, 524288 total
    if (o4 < 524288) {
        int b = o4 >> 17;
        int rem = o4 & 131071;
        ((float4v*)out2)[o4] = ((const float4v*)x)[(size_t)b * 524288 + 393216 + rem];
    }
}

extern "C" void kernel_launch(void* const* d_in, const int* in_sizes, int n_in,
                              void* d_out, int out_size, void* d_ws, size_t ws_size,
                              hipStream_t stream) {
    const float* x = (const float*)d_in[0];
    const float* W_attn = (const float*)d_in[1];
    const float* b_attn = (const float*)d_in[2];
    const float* W_proj = (const float*)d_in[3];
    const float* b_proj = (const float*)d_in[4];
    float* out = (float*)d_out;
    float* out_mem = out + (size_t)8388608;

    char* ws = (char*)d_ws;
    bf16* xb  = (bf16*)(ws);                         // 16MB  [8192][1024]
    bf16* WaT = (bf16*)(ws + ((size_t)16 << 20));    // 6MB   [3072][1024]
    bf16* WpT = (bf16*)(ws + ((size_t)22 << 20));    // 2MB   [1024][1024]
    bf16* q   = (bf16*)(ws + ((size_t)24 << 20));    // 16MB  [B][H][T][64]
    bf16* k   = (bf16*)(ws + ((size_t)40 << 20));    // 16MB  [B][H][T][64]
    bf16* vT  = (bf16*)(ws + ((size_t)56 << 20));    // 16MB  [B][H][64][T]
    bf16* y   = (bf16*)(ws + ((size_t)72 << 20));    // 16MB  [8192][1024]

    k_cast_x<<<8192, 256, 0, stream>>>(x, xb, 2097152);
    k_trans_cast<<<dim3(96, 32), 256, 0, stream>>>(W_attn, WaT, 1024, 3072);
    k_trans_cast<<<dim3(32, 32), 256, 0, stream>>>(W_proj, WpT, 1024, 1024);
    k_gemm_qkv<<<dim3(24, 64), 256, 0, stream>>>(xb, WaT, b_attn, q, k, vT);
    k_attn<<<dim3(16, 64), 256, 0, stream>>>(q, k, vT, y);
    k_gemm_proj<<<dim3(8, 64), 256, 0, stream>>>(y, WpT, b_proj, out);
    k_copy_mem<<<2048, 256, 0, stream>>>(x, out_mem);
}

// Round 2
// 348.416 us; speedup vs baseline: 1.4887x; 1.4887x over previous
//
#include <hip/hip_runtime.h>
#include <hip/hip_bf16.h>

typedef __bf16 bf16;
typedef __bf16 bf16x8 __attribute__((ext_vector_type(8)));
typedef __bf16 bf16x4v __attribute__((ext_vector_type(4)));
typedef float f32x4 __attribute__((ext_vector_type(4)));
typedef float float4v __attribute__((ext_vector_type(4)));

#define MFMA16(a, b, c) __builtin_amdgcn_mfma_f32_16x16x32_bf16(a, b, c, 0, 0, 0)

__device__ __forceinline__ void async_load16(const bf16* g, bf16* l) {
    __builtin_amdgcn_global_load_lds(
        (const __attribute__((address_space(1))) void*)g,
        (__attribute__((address_space(3))) void*)l,
        16, 0, 0);
}

// ---------------- cast x (f32 -> bf16), vectorized ----------------
__global__ void k_cast_x(const float* __restrict__ x, bf16* __restrict__ xb, int n4) {
    int i = blockIdx.x * blockDim.x + threadIdx.x;
    if (i < n4) {
        float4v v = ((const float4v*)x)[i];
        bf16x4v o;
        o.x = (bf16)v.x; o.y = (bf16)v.y; o.z = (bf16)v.z; o.w = (bf16)v.w;
        ((bf16x4v*)xb)[i] = o;
    }
}

// ---------------- transpose + cast W (f32 [R][Cc] -> bf16 [Cc][R]) ----------------
__global__ void k_trans_cast(const float* __restrict__ W, bf16* __restrict__ WT, int R, int Cc) {
    __shared__ float tile[32][33];
    int r0 = blockIdx.y * 32, c0 = blockIdx.x * 32;
    int tx = threadIdx.x & 31, ty = threadIdx.x >> 5;  // 256 thr: ty 0..7
#pragma unroll
    for (int i = 0; i < 32; i += 8)
        tile[ty + i][tx] = W[(size_t)(r0 + ty + i) * Cc + c0 + tx];
    __syncthreads();
#pragma unroll
    for (int i = 0; i < 32; i += 8)
        WT[(size_t)(c0 + ty + i) * R + r0 + tx] = (bf16)tile[tx][ty + i];
}

// ---------------- QKV GEMM: [8192x1024] x [1024x3072] with scatter epilogue ----------------
__global__ __launch_bounds__(256, 2) void k_gemm_qkv(
    const bf16* __restrict__ A, const bf16* __restrict__ BT,
    const float* __restrict__ bias,
    bf16* __restrict__ qo, bf16* __restrict__ ko, bf16* __restrict__ vo) {
    __shared__ bf16 As[128 * 32];
    __shared__ bf16 Bs[128 * 32];
    const int K = 1024;
    int row0 = blockIdx.y * 128;
    int col0 = blockIdx.x * 128;
    int lane = threadIdx.x & 63, w = threadIdx.x >> 6;
    int wr = w >> 1, wc = w & 1;
    f32x4 acc[4][4] = {};
    const bf16* Ag = A + (size_t)(row0 + (lane >> 2)) * K + (lane & 3) * 8;
    const bf16* Bg = BT + (size_t)(col0 + (lane >> 2)) * K + (lane & 3) * 8;

    for (int k0 = 0; k0 < K; k0 += 32) {
#pragma unroll
        for (int i = 0; i < 2; ++i) {
            async_load16(Ag + (size_t)(i * 64 + w * 16) * K + k0, &As[(i * 64 + w * 16) * 32]);
            async_load16(Bg + (size_t)(i * 64 + w * 16) * K + k0, &Bs[(i * 64 + w * 16) * 32]);
        }
        __syncthreads();
        bf16x8 af[4], bfr[4];
#pragma unroll
        for (int m = 0; m < 4; ++m)
            af[m] = *(const bf16x8*)&As[(wr * 64 + m * 16 + (lane & 15)) * 32 + (lane >> 4) * 8];
#pragma unroll
        for (int n = 0; n < 4; ++n)
            bfr[n] = *(const bf16x8*)&Bs[(wc * 64 + n * 16 + (lane & 15)) * 32 + (lane >> 4) * 8];
#pragma unroll
        for (int m = 0; m < 4; ++m)
#pragma unroll
            for (int n = 0; n < 4; ++n)
                acc[m][n] = MFMA16(af[m], bfr[n], acc[m][n]);
        __syncthreads();
    }

    int trow = row0 + wr * 64 + ((lane >> 4) * 4);
    int tcol = col0 + wc * 64 + (lane & 15);
#pragma unroll
    for (int m = 0; m < 4; ++m)
#pragma unroll
        for (int n = 0; n < 4; ++n) {
            int cg = tcol + n * 16;
            float bi = bias[cg];
#pragma unroll
            for (int j = 0; j < 4; ++j) {
                int rg = trow + m * 16 + j;
                float val = acc[m][n][j] + bi;
                bf16 hv = (bf16)val;
                int b = rg >> 11, t = rg & 2047;
                if (cg < 1024) {
                    int h = cg >> 6, d = cg & 63;
                    qo[(size_t)((b * 16 + h) * 2048 + t) * 64 + d] = hv;
                } else if (cg < 2048) {
                    int c2 = cg - 1024;
                    int h = c2 >> 6, d = c2 & 63;
                    ko[(size_t)((b * 16 + h) * 2048 + t) * 64 + d] = hv;
                } else {
                    int c2 = cg - 2048;
                    int h = c2 >> 6, d = c2 & 63;
                    vo[(size_t)((b * 16 + h) * 64 + d) * 2048 + t] = hv;
                }
            }
        }
}

// ---------------- flash attention (causal) ----------------
// 8 waves x 32 Q-rows = 256-row Q-tile per pass; 2 passes (tiles bx and 7-bx)
// for uniform causal work. K/V tiles (64x64) double-buffered in LDS via
// global_load_lds with pre-swizzled SOURCE columns (LDS dest stays linear).
__global__ __launch_bounds__(512, 4) void k_attn(
    const bf16* __restrict__ qg, const bf16* __restrict__ kg,
    const bf16* __restrict__ vg, bf16* __restrict__ y) {
    __shared__ __align__(16) bf16 Ks[2][64 * 64];
    __shared__ __align__(16) bf16 Vs[2][64 * 64];
    __shared__ __align__(16) unsigned char Ps[8][4096];  // per-wave 32x64 bf16 P, swizzled

    int bh = blockIdx.y;
    int b = bh >> 4;
    int lane = threadIdx.x & 63, w = threadIdx.x >> 6;
    const bf16* Qh = qg + (size_t)bh * 2048 * 64;
    const bf16* Kh = kg + (size_t)bh * 2048 * 64;
    const bf16* Vh = vg + (size_t)bh * 64 * 2048;
    unsigned char* myPs = Ps[w];

    // staging coords: thread covers LDS bytes threadIdx.x*16 (row srow, chunk sc16);
    // source column XOR-swizzled so swizzled ds_reads see linear data.
    int srow = threadIdx.x >> 3;                  // 0..63
    int sc16 = threadIdx.x & 7;                   // 16B chunk in row
    int scol8 = ((sc16 ^ (srow & 7)) * 8);        // bf16 elem offset (swizzled src)
    bf16* ldsK0 = &Ks[0][w * 512]; bf16* ldsK1 = &Ks[1][w * 512];
    bf16* ldsV0 = &Vs[0][w * 512]; bf16* ldsV1 = &Vs[1][w * 512];

    for (int qpass = 0; qpass < 2; ++qpass) {
        int qt0 = (qpass == 0 ? (int)blockIdx.x : 7 - (int)blockIdx.x) * 256;
        int trow0 = qt0 + w * 32;

        bf16x8 qf[2][2];
#pragma unroll
        for (int mi = 0; mi < 2; ++mi)
#pragma unroll
            for (int kc = 0; kc < 2; ++kc)
                qf[mi][kc] = *(const bf16x8*)&Qh[(size_t)(trow0 + mi * 16 + (lane & 15)) * 64 + kc * 32 + (lane >> 4) * 8];

        f32x4 acc_o[2][4] = {};
        float mst[2][4], lst[2][4];
#pragma unroll
        for (int mi = 0; mi < 2; ++mi)
#pragma unroll
            for (int j = 0; j < 4; ++j) { mst[mi][j] = -1e30f; lst[mi][j] = 0.f; }

        int ntiles = qt0 / 64 + 4;
        int cur = 0;
        // prologue: stage tile 0 into buf 0
        {
            async_load16(Kh + (size_t)srow * 64 + scol8, ldsK0);
            async_load16(Vh + (size_t)srow * 2048 + scol8, ldsV0);
        }
        __syncthreads();

        for (int ti = 0; ti < ntiles; ++ti) {
            int s0 = ti * 64;
            if (ti + 1 < ntiles) {
                int sn = (ti + 1) * 64;
                async_load16(Kh + (size_t)(sn + srow) * 64 + scol8, cur ? ldsK0 : ldsK1);
                async_load16(Vh + (size_t)srow * 2048 + sn + scol8, cur ? ldsV0 : ldsV1);
            }
            if (s0 < trow0 + 32) {
                const unsigned char* Kc = (const unsigned char*)Ks[cur];
                const unsigned char* Vc = (const unsigned char*)Vs[cur];
                f32x4 accs[2][4] = {};
#pragma unroll
                for (int nt = 0; nt < 4; ++nt)
#pragma unroll
                    for (int kc = 0; kc < 2; ++kc) {
                        int row_s = nt * 16 + (lane & 15);
                        int colb = kc * 64 + (lane >> 4) * 16;
                        bf16x8 kf = *(const bf16x8*)(Kc + row_s * 128 + (colb ^ ((row_s & 7) << 4)));
#pragma unroll
                        for (int mi = 0; mi < 2; ++mi)
                            accs[mi][nt] = MFMA16(qf[mi][kc], kf, accs[mi][nt]);
                    }
                bool diag = (s0 + 63 > trow0);
#pragma unroll
                for (int mi = 0; mi < 2; ++mi) {
                    float corr[4];
#pragma unroll
                    for (int j = 0; j < 4; ++j) {
                        int t = trow0 + mi * 16 + (lane >> 4) * 4 + j;
                        float rm = -1e30f;
#pragma unroll
                        for (int nt = 0; nt < 4; ++nt) {
                            float vsc = accs[mi][nt][j] * 0.125f;
                            if (diag) {
                                int s = s0 + nt * 16 + (lane & 15);
                                if (s > t) vsc = -1e30f;
                            }
                            accs[mi][nt][j] = vsc;
                            rm = fmaxf(rm, vsc);
                        }
#pragma unroll
                        for (int off = 1; off < 16; off <<= 1) rm = fmaxf(rm, __shfl_xor(rm, off));
                        float mo = mst[mi][j];
                        float mn = fmaxf(mo, rm);
                        float c = __expf(mo - mn);
                        float rs = 0.f;
#pragma unroll
                        for (int nt = 0; nt < 4; ++nt) {
                            float p = __expf(accs[mi][nt][j] - mn);
                            accs[mi][nt][j] = p;
                            rs += p;
                        }
#pragma unroll
                        for (int off = 1; off < 16; off <<= 1) rs += __shfl_xor(rs, off);
                        mst[mi][j] = mn;
                        lst[mi][j] = lst[mi][j] * c + rs;
                        corr[j] = c;
                    }
#pragma unroll
                    for (int nt = 0; nt < 4; ++nt)
#pragma unroll
                        for (int j = 0; j < 4; ++j)
                            acc_o[mi][nt][j] *= corr[j];
#pragma unroll
                    for (int nt = 0; nt < 4; ++nt)
#pragma unroll
                        for (int j = 0; j < 4; ++j) {
                            int row = mi * 16 + (lane >> 4) * 4 + j;
                            int byteofs = row * 128 + ((((nt * 16 + (lane & 15)) * 2)) ^ ((row & 7) << 4));
                            *(bf16*)&myPs[byteofs] = (bf16)accs[mi][nt][j];
                        }
                }
                asm volatile("s_waitcnt lgkmcnt(0)" ::: "memory");
                __builtin_amdgcn_sched_barrier(0);
#pragma unroll
                for (int ks = 0; ks < 2; ++ks) {
                    bf16x8 pa[2];
#pragma unroll
                    for (int mi = 0; mi < 2; ++mi) {
                        int row = mi * 16 + (lane & 15);
                        int byteofs = row * 128 + ((ks * 64 + (lane >> 4) * 16) ^ ((row & 7) << 4));
                        pa[mi] = *(const bf16x8*)&myPs[byteofs];
                    }
#pragma unroll
                    for (int nt = 0; nt < 4; ++nt) {
                        int d = nt * 16 + (lane & 15);
                        int colb = ks * 64 + (lane >> 4) * 16;
                        bf16x8 vf = *(const bf16x8*)(Vc + d * 128 + (colb ^ ((d & 7) << 4)));
#pragma unroll
                        for (int mi = 0; mi < 2; ++mi)
                            acc_o[mi][nt] = MFMA16(pa[mi], vf, acc_o[mi][nt]);
                    }
                }
            }
            __syncthreads();   // drains vmcnt (stage writes) + orders buffer reuse
            cur ^= 1;
        }

        int hcol = (bh & 15) * 64;
#pragma unroll
        for (int mi = 0; mi < 2; ++mi)
#pragma unroll
            for (int nt = 0; nt < 4; ++nt)
#pragma unroll
                for (int j = 0; j < 4; ++j) {
                    int t = trow0 + mi * 16 + (lane >> 4) * 4 + j;
                    int d = nt * 16 + (lane & 15);
                    float val = acc_o[mi][nt][j] / lst[mi][j];
                    y[(size_t)(b * 2048 + t) * 1024 + hcol + d] = (bf16)val;
                }
    }
}

// ---------------- proj GEMM: y[8192x1024] x Wp[1024x1024] + bias -> f32 out ----------------
__global__ __launch_bounds__(256, 2) void k_gemm_proj(
    const bf16* __restrict__ A, const bf16* __restrict__ BT,
    const float* __restrict__ bias, float* __restrict__ out) {
    __shared__ bf16 As[128 * 32];
    __shared__ bf16 Bs[128 * 32];
    const int K = 1024;
    int row0 = blockIdx.y * 128;
    int col0 = blockIdx.x * 128;
    int lane = threadIdx.x & 63, w = threadIdx.x >> 6;
    int wr = w >> 1, wc = w & 1;
    f32x4 acc[4][4] = {};
    const bf16* Ag = A + (size_t)(row0 + (lane >> 2)) * K + (lane & 3) * 8;
    const bf16* Bg = BT + (size_t)(col0 + (lane >> 2)) * K + (lane & 3) * 8;

    for (int k0 = 0; k0 < K; k0 += 32) {
#pragma unroll
        for (int i = 0; i < 2; ++i) {
            async_load16(Ag + (size_t)(i * 64 + w * 16) * K + k0, &As[(i * 64 + w * 16) * 32]);
            async_load16(Bg + (size_t)(i * 64 + w * 16) * K + k0, &Bs[(i * 64 + w * 16) * 32]);
        }
        __syncthreads();
        bf16x8 af[4], bfr[4];
#pragma unroll
        for (int m = 0; m < 4; ++m)
            af[m] = *(const bf16x8*)&As[(wr * 64 + m * 16 + (lane & 15)) * 32 + (lane >> 4) * 8];
#pragma unroll
        for (int n = 0; n < 4; ++n)
            bfr[n] = *(const bf16x8*)&Bs[(wc * 64 + n * 16 + (lane & 15)) * 32 + (lane >> 4) * 8];
#pragma unroll
        for (int m = 0; m < 4; ++m)
#pragma unroll
            for (int n = 0; n < 4; ++n)
                acc[m][n] = MFMA16(af[m], bfr[n], acc[m][n]);
        __syncthreads();
    }

    int trow = row0 + wr * 64 + ((lane >> 4) * 4);
    int tcol = col0 + wc * 64 + (lane & 15);
#pragma unroll
    for (int m = 0; m < 4; ++m)
#pragma unroll
        for (int n = 0; n < 4; ++n) {
            int cg = tcol + n * 16;
            float bi = bias[cg];
#pragma unroll
            for (int j = 0; j < 4; ++j) {
                int rg = trow + m * 16 + j;
                out[(size_t)rg * 1024 + cg] = acc[m][n][j] + bi;
            }
        }
}

// ---------------- new_memory = x[:, 1536:, :] (f32 copy) ----------------
__global__ void k_copy_mem(const float* __restrict__ x, float* __restrict__ out2) {
    int o4 = blockIdx.x * blockDim.x + threadIdx.x;  // float4 index, 524288 total
    if (o4 < 524288) {
        int b = o4 >> 17;
        int rem = o4 & 131071;
        ((float4v*)out2)[o4] = ((const float4v*)x)[(size_t)b * 524288 + 393216 + rem];
    }
}

extern "C" void kernel_launch(void* const* d_in, const int* in_sizes, int n_in,
                              void* d_out, int out_size, void* d_ws, size_t ws_size,
                              hipStream_t stream) {
    const float* x = (const float*)d_in[0];
    const float* W_attn = (const float*)d_in[1];
    const float* b_attn = (const float*)d_in[2];
    const float* W_proj = (const float*)d_in[3];
    const float* b_proj = (const float*)d_in[4];
    float* out = (float*)d_out;
    float* out_mem = out + (size_t)8388608;

    char* ws = (char*)d_ws;
    bf16* xb  = (bf16*)(ws);                         // 16MB  [8192][1024]
    bf16* WaT = (bf16*)(ws + ((size_t)16 << 20));    // 6MB   [3072][1024]
    bf16* WpT = (bf16*)(ws + ((size_t)22 << 20));    // 2MB   [1024][1024]
    bf16* q   = (bf16*)(ws + ((size_t)24 << 20));    // 16MB  [B][H][T][64]
    bf16* k   = (bf16*)(ws + ((size_t)40 << 20));    // 16MB  [B][H][T][64]
    bf16* vT  = (bf16*)(ws + ((size_t)56 << 20));    // 16MB  [B][H][64][T]
    bf16* y   = (bf16*)(ws + ((size_t)72 << 20));    // 16MB  [8192][1024]

    k_cast_x<<<8192, 256, 0, stream>>>(x, xb, 2097152);
    k_trans_cast<<<dim3(96, 32), 256, 0, stream>>>(W_attn, WaT, 1024, 3072);
    k_trans_cast<<<dim3(32, 32), 256, 0, stream>>>(W_proj, WpT, 1024, 1024);
    k_gemm_qkv<<<dim3(24, 64), 256, 0, stream>>>(xb, WaT, b_attn, q, k, vT);
    k_attn<<<dim3(4, 64), 512, 0, stream>>>(q, k, vT, y);
    k_gemm_proj<<<dim3(8, 64), 256, 0, stream>>>(y, WpT, b_proj, out);
    k_copy_mem<<<2048, 256, 0, stream>>>(x, out_mem);
}